// Round 8
// baseline (130.706 us; speedup 1.0000x reference)
//
#include <hip/hip_runtime.h>
#include <math.h>

// ---------------------------------------------------------------------------
// HybridQuantumDQN: encoder MLP -> 8-qubit statevector sim -> decoder MLP.
// Round 8: 4 samples/wave64 (16 lanes/sample, 16 complex amps/lane) to double
// the grid's wave count (8192 waves -> ~6-8 waves/SIMD resident; R7's 8
// samples/wave supplied only 4/SIMD and the pk pipe idled ~50%). Keeps all
// prior wins: packed fp32 (v_pk_fma_f32) gates, chunked partner-gather cross
// gates (DPP for xor1/2/8, ds_swizzle for xor4), lane-split encoder/decoder/
// transcendentals, product-state layer 0, closed-form CZ, LDS = coeffs +
// tiny exchange buffers only. __launch_bounds__(256,6) caps VGPR ~85.
//   amp = L*16 + t: L = lane&15 (amp bits 7..4), t = reg idx (bits 3..0).
//   Wires 0..3 cross-lane (xor 8/4/2/1), wires 4..7 in-lane.
// ---------------------------------------------------------------------------

#define PI_F 3.14159265358979323846f

typedef float v2f __attribute__((ext_vector_type(2)));

struct C2 { float re, im; };
__device__ __forceinline__ C2 cmul(C2 a, C2 b) {
    C2 r;
    r.re = fmaf(a.re, b.re, -a.im * b.im);
    r.im = fmaf(a.re, b.im,  a.im * b.re);
    return r;
}
__device__ __forceinline__ float fxor(float x, int m) {
    return __int_as_float(__float_as_int(x) ^ m);
}

// ---------------- packed fp32 primitives (VOP3P) ----------------
__device__ __forceinline__ v2f pk_mul(v2f a, v2f b) {
    v2f d; asm("v_pk_mul_f32 %0, %1, %2" : "=v"(d) : "v"(a), "v"(b)); return d;
}
__device__ __forceinline__ v2f pk_mul_neg(v2f a, v2f b) {
    v2f d; asm("v_pk_mul_f32 %0, %1, %2 neg_lo:[1,0] neg_hi:[1,0]"
               : "=v"(d) : "v"(a), "v"(b)); return d;
}
__device__ __forceinline__ v2f pk_fma(v2f a, v2f b, v2f c) {
    v2f d; asm("v_pk_fma_f32 %0, %1, %2, %3" : "=v"(d) : "v"(a), "v"(b), "v"(c)); return d;
}
// d = -(a*b) + c
__device__ __forceinline__ v2f pk_fma_nn(v2f a, v2f b, v2f c) {
    v2f d; asm("v_pk_fma_f32 %0, %1, %2, %3 neg_lo:[1,0,0] neg_hi:[1,0,0]"
               : "=v"(d) : "v"(a), "v"(b), "v"(c)); return d;
}
// d.lo = -a.lo*b.hi + c.lo ; d.hi = a.hi*b.lo + c.hi   (complex cross term)
__device__ __forceinline__ v2f pk_fma_swl(v2f a, v2f b, v2f c) {
    v2f d; asm("v_pk_fma_f32 %0, %1, %2, %3 op_sel:[0,1,0] op_sel_hi:[1,0,1] neg_lo:[1,0,0]"
               : "=v"(d) : "v"(a), "v"(b), "v"(c)); return d;
}
// d.lo = a.lo*b.hi + c.lo ; d.hi = -a.hi*b.lo + c.hi
__device__ __forceinline__ v2f pk_fma_swh(v2f a, v2f b, v2f c) {
    v2f d; asm("v_pk_fma_f32 %0, %1, %2, %3 op_sel:[0,1,0] op_sel_hi:[1,0,1] neg_hi:[1,0,0]"
               : "=v"(d) : "v"(a), "v"(b), "v"(c)); return d;
}
// z * (re + i*im), complex scalar in C2
__device__ __forceinline__ v2f cmulv(v2f z, C2 c) {
    v2f n = pk_mul((v2f){c.re, c.re}, z);
    return pk_fma_swl((v2f){c.im, c.im}, z, n);
}

// ---------------- cross-lane exchange ----------------
template<int CTRL>
__device__ __forceinline__ float dppf(float x) {
    int xi = __float_as_int(x);
    int r = __builtin_amdgcn_update_dpp(xi, xi, CTRL, 0xF, 0xF, false);
    return __int_as_float(r);
}
template<int M>
__device__ __forceinline__ float lxor(float x) {
    if constexpr (M == 1)      return dppf<0xB1>(x);   // quad_perm [1,0,3,2]
    else if constexpr (M == 2) return dppf<0x4E>(x);   // quad_perm [2,3,0,1]
    else if constexpr (M == 4) return __int_as_float(
        __builtin_amdgcn_ds_swizzle(__float_as_int(x), 0x101F));  // lane^4
    else                       return dppf<0x128>(x);  // row_ror:8 == lane^8 in row16
}

// ---------------- gates ----------------
// fused SU(2) gate G = Rot * RY: columns (a,b); G = [[a,-conj(b)],[b,conj(a)]]
__device__ __forceinline__ void load_G2(const float* __restrict__ c_lds, int g,
                                        float cc, float ss,
                                        float& ar, float& ai, float& br, float& bi) {
    const float4 c0 = *(const float4*)(c_lds + 4 * g);  // aR.re aR.im bR.re bR.im
    ar = fmaf(c0.x, cc, -c0.z * ss);
    ai = fmaf(c0.y, cc,  c0.w * ss);
    br = fmaf(c0.z, cc,  c0.x * ss);
    bi = fmaf(c0.w, cc, -c0.y * ss);
}

// cross-lane SU(2): new = cS*z + cO*p, coeffs pre-sign-adjusted per lane.
// Chunked: gather 8 regs' partners, then the pk ops.
template<int M>
__device__ __forceinline__ void su2_cross(v2f cSr, v2f cSi, v2f cOr, v2f cOi,
                                          v2f z[16]) {
#pragma unroll
    for (int c = 0; c < 2; c++) {
        v2f p[8];
#pragma unroll
        for (int k = 0; k < 8; k++) {
            p[k].x = lxor<M>(z[c * 8 + k].x);
            p[k].y = lxor<M>(z[c * 8 + k].y);
        }
#pragma unroll
        for (int k = 0; k < 8; k++) {
            const int t = c * 8 + k;
            v2f n = pk_mul(cSr, z[t]);
            n = pk_fma_swl(cSi, z[t], n);
            n = pk_fma   (cOr, p[k], n);
            n = pk_fma_swl(cOi, p[k], n);
            z[t] = n;
        }
    }
}

// in-lane SU(2) on reg-index bit ST
template<int ST>
__device__ __forceinline__ void su2_inlane(v2f arr, v2f aii, v2f brr, v2f bii,
                                           v2f z[16]) {
#pragma unroll
    for (int t = 0; t < 16; t++) {
        if ((t & ST) == 0) {
            const int u = t + ST;
            v2f x = z[t], y = z[u];
            v2f nx = pk_mul(arr, x);
            nx = pk_fma_swl(aii, x, nx);
            nx = pk_fma_nn (brr, y, nx);
            nx = pk_fma_swl(bii, y, nx);
            v2f ny = pk_mul(brr, x);
            ny = pk_fma_swl(bii, x, ny);
            ny = pk_fma   (arr, y, ny);
            ny = pk_fma_swh(aii, y, ny);
            z[t] = nx; z[u] = ny;
        }
    }
}

// final RY: cross (cO pre-signed per lane), chunked
template<int M>
__device__ __forceinline__ void ry_cross(v2f cc, v2f cO, v2f z[16]) {
#pragma unroll
    for (int c = 0; c < 2; c++) {
        v2f p[8];
#pragma unroll
        for (int k = 0; k < 8; k++) {
            p[k].x = lxor<M>(z[c * 8 + k].x);
            p[k].y = lxor<M>(z[c * 8 + k].y);
        }
#pragma unroll
        for (int k = 0; k < 8; k++) {
            const int t = c * 8 + k;
            z[t] = pk_fma(cO, p[k], pk_mul(cc, z[t]));
        }
    }
}
template<int ST>
__device__ __forceinline__ void ry_inlane(v2f cc, v2f ss, v2f z[16]) {
#pragma unroll
    for (int t = 0; t < 16; t++) {
        if ((t & ST) == 0) {
            const int u = t + ST;
            v2f x = z[t], y = z[u];
            z[t] = pk_fma_nn(ss, y, pk_mul(cc, x));   // c*x - s*y
            z[u] = pk_fma   (cc, y, pk_mul(ss, x));   // s*x + c*y
        }
    }
}

// CZ t-part (4-bit): parity of adjacent-bit ANDs
__host__ __device__ constexpr bool czt4(int t) {
    return ((((t >> 3) & (t >> 2)) ^ ((t >> 2) & (t >> 1)) ^ ((t >> 1) & t)) & 1) != 0;
}

__global__ __launch_bounds__(256, 6) void qdqn_kernel(
    const float* __restrict__ x,
    const float* __restrict__ ew1, const float* __restrict__ eb1,
    const float* __restrict__ ew2, const float* __restrict__ eb2,
    const float* __restrict__ qw,
    const float* __restrict__ dw1, const float* __restrict__ db1,
    const float* __restrict__ dw2, const float* __restrict__ db2,
    float* __restrict__ out, int B, int NL) {
    __shared__ __align__(16) float c_lds[32 * 4];
    __shared__ __align__(16) float hx[4][4][8];     // h / h2 exchange
    __shared__ __align__(16) float csx[4][4][16];   // (c,s) exchange

    const int tid = threadIdx.x;
    const int wave = tid >> 6;
    const int lane = tid & 63;
    const int grp = lane >> 4;      // sample in wave (0..3)
    const int L = lane & 15;        // amp bits 7..4
    int s = blockIdx.x * 16 + wave * 4 + grp;
    if (s >= B) s = B - 1;

    // ---- prefetch x early (overlaps coef computation + barrier) ----
    float xv[16];
    {
        const float4* xp = (const float4*)(x + s * 16);
#pragma unroll
        for (int i = 0; i < 4; i++) {
            float4 v = xp[i];
            xv[4*i] = v.x; xv[4*i+1] = v.y; xv[4*i+2] = v.z; xv[4*i+3] = v.w;
        }
    }

    // ---- Rot SU(2) coeffs once per block: a = e^{-iA}c, b = e^{-iB}s ----
    const int n_gates = NL * 8;
    if (tid < n_gates) {
        const int gg = tid;
        float phi = qw[3 * gg + 0], th = qw[3 * gg + 1], om = qw[3 * gg + 2];
        float c = __cosf(0.5f * th), sv = __sinf(0.5f * th);
        float A = 0.5f * (phi + om), Bb = 0.5f * (phi - om);
        float* o = c_lds + 4 * gg;
        o[0] =  __cosf(A) * c;   o[1] = -__sinf(A) * c;
        o[2] =  __cosf(Bb) * sv; o[3] = -__sinf(Bb) * sv;
    }
    __syncthreads();

    // ---------------- encoder MLP, split across lanes (row = L&7) ----------
    float cq[8], sq[8];
    {
        const int r = L & 7;
        float a = eb1[r];
#pragma unroll
        for (int i = 0; i < 16; i++) a = fmaf(ew1[r * 16 + i], xv[i], a);
        if (L < 8) hx[wave][grp][r] = fmaxf(a, 0.0f);
        __builtin_amdgcn_wave_barrier();
        float4 h01 = *(const float4*)&hx[wave][grp][0];
        float4 h23 = *(const float4*)&hx[wave][grp][4];
        float b = eb2[r];
        b = fmaf(ew2[r*8+0], h01.x, b); b = fmaf(ew2[r*8+1], h01.y, b);
        b = fmaf(ew2[r*8+2], h01.z, b); b = fmaf(ew2[r*8+3], h01.w, b);
        b = fmaf(ew2[r*8+4], h23.x, b); b = fmaf(ew2[r*8+5], h23.y, b);
        b = fmaf(ew2[r*8+6], h23.z, b); b = fmaf(ew2[r*8+7], h23.w, b);
        float e = 1.0f - __fdividef(2.0f, __expf(2.0f * b) + 1.0f);  // tanh
        float ang = e * (0.5f * PI_F);
        if (L < 8) {
            float2* cso = (float2*)&csx[wave][grp][2 * r];
            *cso = make_float2(__cosf(ang), __sinf(ang));
        }
        __builtin_amdgcn_wave_barrier();
#pragma unroll
        for (int k = 0; k < 4; k++) {
            float4 v = *(const float4*)&csx[wave][grp][4 * k];
            cq[2*k] = v.x; sq[2*k] = v.y; cq[2*k+1] = v.z; sq[2*k+1] = v.w;
        }
    }

    // ---- per-lane sign masks for cross wires q=0..3 (bit 3-q of L) ----
    int hiM[4], loM[4];
#pragma unroll
    for (int q = 0; q < 4; q++) {
        int hi = (L >> (3 - q)) & 1;
        hiM[q] = hi << 31;                 // flips ai when hi lane
        loM[q] = hiM[q] ^ 0x80000000;      // flips br when lo lane
    }

    // ---- CZ lane scalars (hi nibble = L, lo nibble = t) ----
    const int L0 = L & 1, L1b = (L >> 1) & 1, L2b = (L >> 2) & 1, L3b = (L >> 3) & 1;
    const int cnt = (L3b & L2b) ^ (L2b & L1b) ^ (L1b & L0);
    const float mL = cnt ? -1.0f : 1.0f;   // t < 8
    const float mH = L0 ? -mL : mL;        // t >= 8 adds (L0 & t3)
    const v2f mL2 = (v2f){mL, mL}, mH2 = (v2f){mH, mH};

    // ---------------- layer 0: product state, CZ folded --------------------
    v2f z[16];
    {
        C2 P; P.re = 1.0f; P.im = 0.0f;
        C2 F[4][2];
#pragma unroll
        for (int q = 0; q < 8; q++) {
            float ar, ai, br, bi;
            load_G2(c_lds, q, cq[q], sq[q], ar, ai, br, bi);
            if (q < 4) {
                const bool hi = (L >> (3 - q)) & 1;
                C2 f; f.re = hi ? br : ar; f.im = hi ? bi : ai;  // column 0
                P = cmul(P, f);
            } else {
                F[q-4][0].re = ar; F[q-4][0].im = ai;
                F[q-4][1].re = br; F[q-4][1].im = bi;
            }
        }
        z[0] = (v2f){P.re, P.im};
#pragma unroll
        for (int w = 0; w < 4; w++) {
            const int n = 1 << w;
#pragma unroll
            for (int i = n - 1; i >= 0; i--) {
                v2f v = z[i];
                z[2*i+1] = cmulv(v, F[w][1]);
                z[2*i]   = cmulv(v, F[w][0]);
            }
        }
#pragma unroll
        for (int t = 0; t < 16; t++) {
            v2f m = (t < 8) ? mL2 : mH2;
            z[t] = czt4(t) ? pk_mul_neg(m, z[t]) : pk_mul(m, z[t]);
        }
    }

    // ---------------- layers 1..NL-1 ---------------------------------------
    for (int l = 1; l < NL; l++) {
        const int gb = l * 8;
        float ar, ai, br, bi;
        load_G2(c_lds, gb+0, cq[0], sq[0], ar, ai, br, bi);
        su2_cross<8>((v2f){ar,ar}, (v2f){fxor(ai,hiM[0]),fxor(ai,hiM[0])},
                     (v2f){fxor(br,loM[0]),fxor(br,loM[0])}, (v2f){bi,bi}, z);
        load_G2(c_lds, gb+1, cq[1], sq[1], ar, ai, br, bi);
        su2_cross<4>((v2f){ar,ar}, (v2f){fxor(ai,hiM[1]),fxor(ai,hiM[1])},
                     (v2f){fxor(br,loM[1]),fxor(br,loM[1])}, (v2f){bi,bi}, z);
        load_G2(c_lds, gb+2, cq[2], sq[2], ar, ai, br, bi);
        su2_cross<2>((v2f){ar,ar}, (v2f){fxor(ai,hiM[2]),fxor(ai,hiM[2])},
                     (v2f){fxor(br,loM[2]),fxor(br,loM[2])}, (v2f){bi,bi}, z);
        load_G2(c_lds, gb+3, cq[3], sq[3], ar, ai, br, bi);
        su2_cross<1>((v2f){ar,ar}, (v2f){fxor(ai,hiM[3]),fxor(ai,hiM[3])},
                     (v2f){fxor(br,loM[3]),fxor(br,loM[3])}, (v2f){bi,bi}, z);
        load_G2(c_lds, gb+4, cq[4], sq[4], ar, ai, br, bi);
        su2_inlane<8>((v2f){ar,ar}, (v2f){ai,ai}, (v2f){br,br}, (v2f){bi,bi}, z);
        load_G2(c_lds, gb+5, cq[5], sq[5], ar, ai, br, bi);
        su2_inlane<4>((v2f){ar,ar}, (v2f){ai,ai}, (v2f){br,br}, (v2f){bi,bi}, z);
        load_G2(c_lds, gb+6, cq[6], sq[6], ar, ai, br, bi);
        su2_inlane<2>((v2f){ar,ar}, (v2f){ai,ai}, (v2f){br,br}, (v2f){bi,bi}, z);
        load_G2(c_lds, gb+7, cq[7], sq[7], ar, ai, br, bi);
        su2_inlane<1>((v2f){ar,ar}, (v2f){ai,ai}, (v2f){br,br}, (v2f){bi,bi}, z);
#pragma unroll
        for (int t = 0; t < 16; t++) {
            v2f m = (t < 8) ? mL2 : mH2;
            z[t] = czt4(t) ? pk_mul_neg(m, z[t]) : pk_mul(m, z[t]);
        }
    }

    // ---------------- final RY layer ---------------------------------------
    {
        v2f cc, cO, ss;
        cc=(v2f){cq[0],cq[0]}; cO=(v2f){fxor(sq[0],loM[0]),fxor(sq[0],loM[0])};
        ry_cross<8>(cc, cO, z);
        cc=(v2f){cq[1],cq[1]}; cO=(v2f){fxor(sq[1],loM[1]),fxor(sq[1],loM[1])};
        ry_cross<4>(cc, cO, z);
        cc=(v2f){cq[2],cq[2]}; cO=(v2f){fxor(sq[2],loM[2]),fxor(sq[2],loM[2])};
        ry_cross<2>(cc, cO, z);
        cc=(v2f){cq[3],cq[3]}; cO=(v2f){fxor(sq[3],loM[3]),fxor(sq[3],loM[3])};
        ry_cross<1>(cc, cO, z);
        cc=(v2f){cq[4],cq[4]}; ss=(v2f){sq[4],sq[4]}; ry_inlane<8>(cc, ss, z);
        cc=(v2f){cq[5],cq[5]}; ss=(v2f){sq[5],sq[5]}; ry_inlane<4>(cc, ss, z);
        cc=(v2f){cq[6],cq[6]}; ss=(v2f){sq[6],sq[6]}; ry_inlane<2>(cc, ss, z);
        cc=(v2f){cq[7],cq[7]}; ss=(v2f){sq[7],sq[7]}; ry_inlane<1>(cc, ss, z);
    }

    // ---------------- probs -> <Z_w> ----------------
    float p[16];
#pragma unroll
    for (int t = 0; t < 16; t++) p[t] = fmaf(z[t].x, z[t].x, z[t].y * z[t].y);

    float e0 = p[0]+p[1],  e1 = p[2]+p[3],  e2 = p[4]+p[5],  e3 = p[6]+p[7];
    float e4 = p[8]+p[9],  e5 = p[10]+p[11], e6 = p[12]+p[13], e7 = p[14]+p[15];
    float q0 = e0+e1, q1 = e2+e3, q2 = e4+e5, q3 = e6+e7;
    float h0 = q0+q1, h1 = q2+q3;
    float sumP = h0 + h1;

    float zW[8];
    zW[0] = L3b ? -sumP : sumP;
    zW[1] = L2b ? -sumP : sumP;
    zW[2] = L1b ? -sumP : sumP;
    zW[3] = L0  ? -sumP : sumP;
    zW[4] = h0 - h1;
    zW[5] = (q0 - q1) + (q2 - q3);
    zW[6] = (e0 - e1) + (e2 - e3) + (e4 - e5) + (e6 - e7);
    zW[7] = (p[0]-p[1]) + (p[2]-p[3]) + (p[4]-p[5]) + (p[6]-p[7])
          + (p[8]-p[9]) + (p[10]-p[11]) + (p[12]-p[13]) + (p[14]-p[15]);

    // reduce across the 16-lane sample group
#pragma unroll
    for (int w = 0; w < 8; w++) zW[w] += lxor<1>(zW[w]);
#pragma unroll
    for (int w = 0; w < 8; w++) zW[w] += lxor<2>(zW[w]);
#pragma unroll
    for (int w = 0; w < 8; w++) zW[w] += lxor<4>(zW[w]);
#pragma unroll
    for (int w = 0; w < 8; w++) zW[w] += lxor<8>(zW[w]);

    // ---------------- decoder MLP, split across lanes ----------------------
    {
        const int r = L & 7;
        float a = db1[r];
#pragma unroll
        for (int w = 0; w < 8; w++) a = fmaf(dw1[r * 8 + w], zW[w], a);
        if (L < 8) hx[wave][grp][r] = fmaxf(a, 0.0f);
        __builtin_amdgcn_wave_barrier();
        if (L < 4) {
            float4 h01 = *(const float4*)&hx[wave][grp][0];
            float4 h23 = *(const float4*)&hx[wave][grp][4];
            float acc = db2[L];
            acc = fmaf(dw2[L*8+0], h01.x, acc); acc = fmaf(dw2[L*8+1], h01.y, acc);
            acc = fmaf(dw2[L*8+2], h01.z, acc); acc = fmaf(dw2[L*8+3], h01.w, acc);
            acc = fmaf(dw2[L*8+4], h23.x, acc); acc = fmaf(dw2[L*8+5], h23.y, acc);
            acc = fmaf(dw2[L*8+6], h23.z, acc); acc = fmaf(dw2[L*8+7], h23.w, acc);
            out[s * 4 + L] = acc;
        }
    }
}

extern "C" void kernel_launch(void* const* d_in, const int* in_sizes, int n_in,
                              void* d_out, int out_size, void* d_ws, size_t ws_size,
                              hipStream_t stream) {
    const float* x   = (const float*)d_in[0];
    const float* ew1 = (const float*)d_in[1];
    const float* eb1 = (const float*)d_in[2];
    const float* ew2 = (const float*)d_in[3];
    const float* eb2 = (const float*)d_in[4];
    const float* qw  = (const float*)d_in[5];
    const float* dw1 = (const float*)d_in[6];
    const float* db1 = (const float*)d_in[7];
    const float* dw2 = (const float*)d_in[8];
    const float* db2 = (const float*)d_in[9];
    float* out = (float*)d_out;

    int B = in_sizes[0] / 16;        // 32768
    int n_gates = in_sizes[5] / 3;   // 32
    int NL = n_gates / 8;            // 4

    // 16 samples per 256-thread block (4 waves x 4 samples/wave) -> 8192 waves
    int blocks = (B + 15) / 16;
    qdqn_kernel<<<blocks, 256, 0, stream>>>(x, ew1, eb1, ew2, eb2, qw,
                                            dw1, db1, dw2, db2, out, B, NL);
}

// Round 9
// 121.939 us; speedup vs baseline: 1.0719x; 1.0719x over previous
//
#include <hip/hip_runtime.h>
#include <math.h>

// ---------------------------------------------------------------------------
// HybridQuantumDQN: encoder MLP -> 8-qubit statevector sim -> decoder MLP.
// Round 9: identical to Round 8 EXCEPT __launch_bounds__(256, 4).
// R8's (256,6) forced the allocator to ~40 VGPRs < the 32-reg statevector ->
// spilled state to scratch (FETCH 36MB / WRITE 62MB per dispatch, ~100MB HBM
// round-trips). (256,4) caps at 128 VGPR; kernel wants ~90 -> no spill, and
// the 8192-wave grid supplies ~4+ waves/SIMD for latency hiding.
//   4 samples/wave64; 16 lanes/sample; 16 complex amps/lane (v2f).
//   amp = L*16 + t: L = lane&15 (amp bits 7..4), t = reg idx (bits 3..0).
//   Wires 0..3 cross-lane (xor 8/4/2/1: DPP + one ds_swizzle), 4..7 in-lane.
//   Packed fp32 (v_pk_fma_f32) gates; lane-split MLPs/transcendentals;
//   product-state layer 0; closed-form CZ diagonal.
// ---------------------------------------------------------------------------

#define PI_F 3.14159265358979323846f

typedef float v2f __attribute__((ext_vector_type(2)));

struct C2 { float re, im; };
__device__ __forceinline__ C2 cmul(C2 a, C2 b) {
    C2 r;
    r.re = fmaf(a.re, b.re, -a.im * b.im);
    r.im = fmaf(a.re, b.im,  a.im * b.re);
    return r;
}
__device__ __forceinline__ float fxor(float x, int m) {
    return __int_as_float(__float_as_int(x) ^ m);
}

// ---------------- packed fp32 primitives (VOP3P) ----------------
__device__ __forceinline__ v2f pk_mul(v2f a, v2f b) {
    v2f d; asm("v_pk_mul_f32 %0, %1, %2" : "=v"(d) : "v"(a), "v"(b)); return d;
}
__device__ __forceinline__ v2f pk_mul_neg(v2f a, v2f b) {
    v2f d; asm("v_pk_mul_f32 %0, %1, %2 neg_lo:[1,0] neg_hi:[1,0]"
               : "=v"(d) : "v"(a), "v"(b)); return d;
}
__device__ __forceinline__ v2f pk_fma(v2f a, v2f b, v2f c) {
    v2f d; asm("v_pk_fma_f32 %0, %1, %2, %3" : "=v"(d) : "v"(a), "v"(b), "v"(c)); return d;
}
// d = -(a*b) + c
__device__ __forceinline__ v2f pk_fma_nn(v2f a, v2f b, v2f c) {
    v2f d; asm("v_pk_fma_f32 %0, %1, %2, %3 neg_lo:[1,0,0] neg_hi:[1,0,0]"
               : "=v"(d) : "v"(a), "v"(b), "v"(c)); return d;
}
// d.lo = -a.lo*b.hi + c.lo ; d.hi = a.hi*b.lo + c.hi   (complex cross term)
__device__ __forceinline__ v2f pk_fma_swl(v2f a, v2f b, v2f c) {
    v2f d; asm("v_pk_fma_f32 %0, %1, %2, %3 op_sel:[0,1,0] op_sel_hi:[1,0,1] neg_lo:[1,0,0]"
               : "=v"(d) : "v"(a), "v"(b), "v"(c)); return d;
}
// d.lo = a.lo*b.hi + c.lo ; d.hi = -a.hi*b.lo + c.hi
__device__ __forceinline__ v2f pk_fma_swh(v2f a, v2f b, v2f c) {
    v2f d; asm("v_pk_fma_f32 %0, %1, %2, %3 op_sel:[0,1,0] op_sel_hi:[1,0,1] neg_hi:[1,0,0]"
               : "=v"(d) : "v"(a), "v"(b), "v"(c)); return d;
}
// z * (re + i*im), complex scalar in C2
__device__ __forceinline__ v2f cmulv(v2f z, C2 c) {
    v2f n = pk_mul((v2f){c.re, c.re}, z);
    return pk_fma_swl((v2f){c.im, c.im}, z, n);
}

// ---------------- cross-lane exchange ----------------
template<int CTRL>
__device__ __forceinline__ float dppf(float x) {
    int xi = __float_as_int(x);
    int r = __builtin_amdgcn_update_dpp(xi, xi, CTRL, 0xF, 0xF, false);
    return __int_as_float(r);
}
template<int M>
__device__ __forceinline__ float lxor(float x) {
    if constexpr (M == 1)      return dppf<0xB1>(x);   // quad_perm [1,0,3,2]
    else if constexpr (M == 2) return dppf<0x4E>(x);   // quad_perm [2,3,0,1]
    else if constexpr (M == 4) return __int_as_float(
        __builtin_amdgcn_ds_swizzle(__float_as_int(x), 0x101F));  // lane^4
    else                       return dppf<0x128>(x);  // row_ror:8 == lane^8 in row16
}

// ---------------- gates ----------------
// fused SU(2) gate G = Rot * RY: columns (a,b); G = [[a,-conj(b)],[b,conj(a)]]
__device__ __forceinline__ void load_G2(const float* __restrict__ c_lds, int g,
                                        float cc, float ss,
                                        float& ar, float& ai, float& br, float& bi) {
    const float4 c0 = *(const float4*)(c_lds + 4 * g);  // aR.re aR.im bR.re bR.im
    ar = fmaf(c0.x, cc, -c0.z * ss);
    ai = fmaf(c0.y, cc,  c0.w * ss);
    br = fmaf(c0.z, cc,  c0.x * ss);
    bi = fmaf(c0.w, cc, -c0.y * ss);
}

// cross-lane SU(2): new = cS*z + cO*p, coeffs pre-sign-adjusted per lane.
// Chunked: gather 8 regs' partners, then the pk ops.
template<int M>
__device__ __forceinline__ void su2_cross(v2f cSr, v2f cSi, v2f cOr, v2f cOi,
                                          v2f z[16]) {
#pragma unroll
    for (int c = 0; c < 2; c++) {
        v2f p[8];
#pragma unroll
        for (int k = 0; k < 8; k++) {
            p[k].x = lxor<M>(z[c * 8 + k].x);
            p[k].y = lxor<M>(z[c * 8 + k].y);
        }
#pragma unroll
        for (int k = 0; k < 8; k++) {
            const int t = c * 8 + k;
            v2f n = pk_mul(cSr, z[t]);
            n = pk_fma_swl(cSi, z[t], n);
            n = pk_fma   (cOr, p[k], n);
            n = pk_fma_swl(cOi, p[k], n);
            z[t] = n;
        }
    }
}

// in-lane SU(2) on reg-index bit ST
template<int ST>
__device__ __forceinline__ void su2_inlane(v2f arr, v2f aii, v2f brr, v2f bii,
                                           v2f z[16]) {
#pragma unroll
    for (int t = 0; t < 16; t++) {
        if ((t & ST) == 0) {
            const int u = t + ST;
            v2f x = z[t], y = z[u];
            v2f nx = pk_mul(arr, x);
            nx = pk_fma_swl(aii, x, nx);
            nx = pk_fma_nn (brr, y, nx);
            nx = pk_fma_swl(bii, y, nx);
            v2f ny = pk_mul(brr, x);
            ny = pk_fma_swl(bii, x, ny);
            ny = pk_fma   (arr, y, ny);
            ny = pk_fma_swh(aii, y, ny);
            z[t] = nx; z[u] = ny;
        }
    }
}

// final RY: cross (cO pre-signed per lane), chunked
template<int M>
__device__ __forceinline__ void ry_cross(v2f cc, v2f cO, v2f z[16]) {
#pragma unroll
    for (int c = 0; c < 2; c++) {
        v2f p[8];
#pragma unroll
        for (int k = 0; k < 8; k++) {
            p[k].x = lxor<M>(z[c * 8 + k].x);
            p[k].y = lxor<M>(z[c * 8 + k].y);
        }
#pragma unroll
        for (int k = 0; k < 8; k++) {
            const int t = c * 8 + k;
            z[t] = pk_fma(cO, p[k], pk_mul(cc, z[t]));
        }
    }
}
template<int ST>
__device__ __forceinline__ void ry_inlane(v2f cc, v2f ss, v2f z[16]) {
#pragma unroll
    for (int t = 0; t < 16; t++) {
        if ((t & ST) == 0) {
            const int u = t + ST;
            v2f x = z[t], y = z[u];
            z[t] = pk_fma_nn(ss, y, pk_mul(cc, x));   // c*x - s*y
            z[u] = pk_fma   (cc, y, pk_mul(ss, x));   // s*x + c*y
        }
    }
}

// CZ t-part (4-bit): parity of adjacent-bit ANDs
__host__ __device__ constexpr bool czt4(int t) {
    return ((((t >> 3) & (t >> 2)) ^ ((t >> 2) & (t >> 1)) ^ ((t >> 1) & t)) & 1) != 0;
}

__global__ __launch_bounds__(256, 4) void qdqn_kernel(
    const float* __restrict__ x,
    const float* __restrict__ ew1, const float* __restrict__ eb1,
    const float* __restrict__ ew2, const float* __restrict__ eb2,
    const float* __restrict__ qw,
    const float* __restrict__ dw1, const float* __restrict__ db1,
    const float* __restrict__ dw2, const float* __restrict__ db2,
    float* __restrict__ out, int B, int NL) {
    __shared__ __align__(16) float c_lds[32 * 4];
    __shared__ __align__(16) float hx[4][4][8];     // h / h2 exchange
    __shared__ __align__(16) float csx[4][4][16];   // (c,s) exchange

    const int tid = threadIdx.x;
    const int wave = tid >> 6;
    const int lane = tid & 63;
    const int grp = lane >> 4;      // sample in wave (0..3)
    const int L = lane & 15;        // amp bits 7..4
    int s = blockIdx.x * 16 + wave * 4 + grp;
    if (s >= B) s = B - 1;

    // ---- prefetch x early (overlaps coef computation + barrier) ----
    float xv[16];
    {
        const float4* xp = (const float4*)(x + s * 16);
#pragma unroll
        for (int i = 0; i < 4; i++) {
            float4 v = xp[i];
            xv[4*i] = v.x; xv[4*i+1] = v.y; xv[4*i+2] = v.z; xv[4*i+3] = v.w;
        }
    }

    // ---- Rot SU(2) coeffs once per block: a = e^{-iA}c, b = e^{-iB}s ----
    const int n_gates = NL * 8;
    if (tid < n_gates) {
        const int gg = tid;
        float phi = qw[3 * gg + 0], th = qw[3 * gg + 1], om = qw[3 * gg + 2];
        float c = __cosf(0.5f * th), sv = __sinf(0.5f * th);
        float A = 0.5f * (phi + om), Bb = 0.5f * (phi - om);
        float* o = c_lds + 4 * gg;
        o[0] =  __cosf(A) * c;   o[1] = -__sinf(A) * c;
        o[2] =  __cosf(Bb) * sv; o[3] = -__sinf(Bb) * sv;
    }
    __syncthreads();

    // ---------------- encoder MLP, split across lanes (row = L&7) ----------
    float cq[8], sq[8];
    {
        const int r = L & 7;
        float a = eb1[r];
#pragma unroll
        for (int i = 0; i < 16; i++) a = fmaf(ew1[r * 16 + i], xv[i], a);
        if (L < 8) hx[wave][grp][r] = fmaxf(a, 0.0f);
        __builtin_amdgcn_wave_barrier();
        float4 h01 = *(const float4*)&hx[wave][grp][0];
        float4 h23 = *(const float4*)&hx[wave][grp][4];
        float b = eb2[r];
        b = fmaf(ew2[r*8+0], h01.x, b); b = fmaf(ew2[r*8+1], h01.y, b);
        b = fmaf(ew2[r*8+2], h01.z, b); b = fmaf(ew2[r*8+3], h01.w, b);
        b = fmaf(ew2[r*8+4], h23.x, b); b = fmaf(ew2[r*8+5], h23.y, b);
        b = fmaf(ew2[r*8+6], h23.z, b); b = fmaf(ew2[r*8+7], h23.w, b);
        float e = 1.0f - __fdividef(2.0f, __expf(2.0f * b) + 1.0f);  // tanh
        float ang = e * (0.5f * PI_F);
        if (L < 8) {
            float2* cso = (float2*)&csx[wave][grp][2 * r];
            *cso = make_float2(__cosf(ang), __sinf(ang));
        }
        __builtin_amdgcn_wave_barrier();
#pragma unroll
        for (int k = 0; k < 4; k++) {
            float4 v = *(const float4*)&csx[wave][grp][4 * k];
            cq[2*k] = v.x; sq[2*k] = v.y; cq[2*k+1] = v.z; sq[2*k+1] = v.w;
        }
    }

    // ---- per-lane sign masks for cross wires q=0..3 (bit 3-q of L) ----
    int hiM[4], loM[4];
#pragma unroll
    for (int q = 0; q < 4; q++) {
        int hi = (L >> (3 - q)) & 1;
        hiM[q] = hi << 31;                 // flips ai when hi lane
        loM[q] = hiM[q] ^ 0x80000000;      // flips br when lo lane
    }

    // ---- CZ lane scalars (hi nibble = L, lo nibble = t) ----
    const int L0 = L & 1, L1b = (L >> 1) & 1, L2b = (L >> 2) & 1, L3b = (L >> 3) & 1;
    const int cnt = (L3b & L2b) ^ (L2b & L1b) ^ (L1b & L0);
    const float mL = cnt ? -1.0f : 1.0f;   // t < 8
    const float mH = L0 ? -mL : mL;        // t >= 8 adds (L0 & t3)
    const v2f mL2 = (v2f){mL, mL}, mH2 = (v2f){mH, mH};

    // ---------------- layer 0: product state, CZ folded --------------------
    v2f z[16];
    {
        C2 P; P.re = 1.0f; P.im = 0.0f;
        C2 F[4][2];
#pragma unroll
        for (int q = 0; q < 8; q++) {
            float ar, ai, br, bi;
            load_G2(c_lds, q, cq[q], sq[q], ar, ai, br, bi);
            if (q < 4) {
                const bool hi = (L >> (3 - q)) & 1;
                C2 f; f.re = hi ? br : ar; f.im = hi ? bi : ai;  // column 0
                P = cmul(P, f);
            } else {
                F[q-4][0].re = ar; F[q-4][0].im = ai;
                F[q-4][1].re = br; F[q-4][1].im = bi;
            }
        }
        z[0] = (v2f){P.re, P.im};
#pragma unroll
        for (int w = 0; w < 4; w++) {
            const int n = 1 << w;
#pragma unroll
            for (int i = n - 1; i >= 0; i--) {
                v2f v = z[i];
                z[2*i+1] = cmulv(v, F[w][1]);
                z[2*i]   = cmulv(v, F[w][0]);
            }
        }
#pragma unroll
        for (int t = 0; t < 16; t++) {
            v2f m = (t < 8) ? mL2 : mH2;
            z[t] = czt4(t) ? pk_mul_neg(m, z[t]) : pk_mul(m, z[t]);
        }
    }

    // ---------------- layers 1..NL-1 ---------------------------------------
    for (int l = 1; l < NL; l++) {
        const int gb = l * 8;
        float ar, ai, br, bi;
        load_G2(c_lds, gb+0, cq[0], sq[0], ar, ai, br, bi);
        su2_cross<8>((v2f){ar,ar}, (v2f){fxor(ai,hiM[0]),fxor(ai,hiM[0])},
                     (v2f){fxor(br,loM[0]),fxor(br,loM[0])}, (v2f){bi,bi}, z);
        load_G2(c_lds, gb+1, cq[1], sq[1], ar, ai, br, bi);
        su2_cross<4>((v2f){ar,ar}, (v2f){fxor(ai,hiM[1]),fxor(ai,hiM[1])},
                     (v2f){fxor(br,loM[1]),fxor(br,loM[1])}, (v2f){bi,bi}, z);
        load_G2(c_lds, gb+2, cq[2], sq[2], ar, ai, br, bi);
        su2_cross<2>((v2f){ar,ar}, (v2f){fxor(ai,hiM[2]),fxor(ai,hiM[2])},
                     (v2f){fxor(br,loM[2]),fxor(br,loM[2])}, (v2f){bi,bi}, z);
        load_G2(c_lds, gb+3, cq[3], sq[3], ar, ai, br, bi);
        su2_cross<1>((v2f){ar,ar}, (v2f){fxor(ai,hiM[3]),fxor(ai,hiM[3])},
                     (v2f){fxor(br,loM[3]),fxor(br,loM[3])}, (v2f){bi,bi}, z);
        load_G2(c_lds, gb+4, cq[4], sq[4], ar, ai, br, bi);
        su2_inlane<8>((v2f){ar,ar}, (v2f){ai,ai}, (v2f){br,br}, (v2f){bi,bi}, z);
        load_G2(c_lds, gb+5, cq[5], sq[5], ar, ai, br, bi);
        su2_inlane<4>((v2f){ar,ar}, (v2f){ai,ai}, (v2f){br,br}, (v2f){bi,bi}, z);
        load_G2(c_lds, gb+6, cq[6], sq[6], ar, ai, br, bi);
        su2_inlane<2>((v2f){ar,ar}, (v2f){ai,ai}, (v2f){br,br}, (v2f){bi,bi}, z);
        load_G2(c_lds, gb+7, cq[7], sq[7], ar, ai, br, bi);
        su2_inlane<1>((v2f){ar,ar}, (v2f){ai,ai}, (v2f){br,br}, (v2f){bi,bi}, z);
#pragma unroll
        for (int t = 0; t < 16; t++) {
            v2f m = (t < 8) ? mL2 : mH2;
            z[t] = czt4(t) ? pk_mul_neg(m, z[t]) : pk_mul(m, z[t]);
        }
    }

    // ---------------- final RY layer ---------------------------------------
    {
        v2f cc, cO, ss;
        cc=(v2f){cq[0],cq[0]}; cO=(v2f){fxor(sq[0],loM[0]),fxor(sq[0],loM[0])};
        ry_cross<8>(cc, cO, z);
        cc=(v2f){cq[1],cq[1]}; cO=(v2f){fxor(sq[1],loM[1]),fxor(sq[1],loM[1])};
        ry_cross<4>(cc, cO, z);
        cc=(v2f){cq[2],cq[2]}; cO=(v2f){fxor(sq[2],loM[2]),fxor(sq[2],loM[2])};
        ry_cross<2>(cc, cO, z);
        cc=(v2f){cq[3],cq[3]}; cO=(v2f){fxor(sq[3],loM[3]),fxor(sq[3],loM[3])};
        ry_cross<1>(cc, cO, z);
        cc=(v2f){cq[4],cq[4]}; ss=(v2f){sq[4],sq[4]}; ry_inlane<8>(cc, ss, z);
        cc=(v2f){cq[5],cq[5]}; ss=(v2f){sq[5],sq[5]}; ry_inlane<4>(cc, ss, z);
        cc=(v2f){cq[6],cq[6]}; ss=(v2f){sq[6],sq[6]}; ry_inlane<2>(cc, ss, z);
        cc=(v2f){cq[7],cq[7]}; ss=(v2f){sq[7],sq[7]}; ry_inlane<1>(cc, ss, z);
    }

    // ---------------- probs -> <Z_w> ----------------
    float p[16];
#pragma unroll
    for (int t = 0; t < 16; t++) p[t] = fmaf(z[t].x, z[t].x, z[t].y * z[t].y);

    float e0 = p[0]+p[1],  e1 = p[2]+p[3],  e2 = p[4]+p[5],  e3 = p[6]+p[7];
    float e4 = p[8]+p[9],  e5 = p[10]+p[11], e6 = p[12]+p[13], e7 = p[14]+p[15];
    float q0 = e0+e1, q1 = e2+e3, q2 = e4+e5, q3 = e6+e7;
    float h0 = q0+q1, h1 = q2+q3;
    float sumP = h0 + h1;

    float zW[8];
    zW[0] = L3b ? -sumP : sumP;
    zW[1] = L2b ? -sumP : sumP;
    zW[2] = L1b ? -sumP : sumP;
    zW[3] = L0  ? -sumP : sumP;
    zW[4] = h0 - h1;
    zW[5] = (q0 - q1) + (q2 - q3);
    zW[6] = (e0 - e1) + (e2 - e3) + (e4 - e5) + (e6 - e7);
    zW[7] = (p[0]-p[1]) + (p[2]-p[3]) + (p[4]-p[5]) + (p[6]-p[7])
          + (p[8]-p[9]) + (p[10]-p[11]) + (p[12]-p[13]) + (p[14]-p[15]);

    // reduce across the 16-lane sample group
#pragma unroll
    for (int w = 0; w < 8; w++) zW[w] += lxor<1>(zW[w]);
#pragma unroll
    for (int w = 0; w < 8; w++) zW[w] += lxor<2>(zW[w]);
#pragma unroll
    for (int w = 0; w < 8; w++) zW[w] += lxor<4>(zW[w]);
#pragma unroll
    for (int w = 0; w < 8; w++) zW[w] += lxor<8>(zW[w]);

    // ---------------- decoder MLP, split across lanes ----------------------
    {
        const int r = L & 7;
        float a = db1[r];
#pragma unroll
        for (int w = 0; w < 8; w++) a = fmaf(dw1[r * 8 + w], zW[w], a);
        if (L < 8) hx[wave][grp][r] = fmaxf(a, 0.0f);
        __builtin_amdgcn_wave_barrier();
        if (L < 4) {
            float4 h01 = *(const float4*)&hx[wave][grp][0];
            float4 h23 = *(const float4*)&hx[wave][grp][4];
            float acc = db2[L];
            acc = fmaf(dw2[L*8+0], h01.x, acc); acc = fmaf(dw2[L*8+1], h01.y, acc);
            acc = fmaf(dw2[L*8+2], h01.z, acc); acc = fmaf(dw2[L*8+3], h01.w, acc);
            acc = fmaf(dw2[L*8+4], h23.x, acc); acc = fmaf(dw2[L*8+5], h23.y, acc);
            acc = fmaf(dw2[L*8+6], h23.z, acc); acc = fmaf(dw2[L*8+7], h23.w, acc);
            out[s * 4 + L] = acc;
        }
    }
}

extern "C" void kernel_launch(void* const* d_in, const int* in_sizes, int n_in,
                              void* d_out, int out_size, void* d_ws, size_t ws_size,
                              hipStream_t stream) {
    const float* x   = (const float*)d_in[0];
    const float* ew1 = (const float*)d_in[1];
    const float* eb1 = (const float*)d_in[2];
    const float* ew2 = (const float*)d_in[3];
    const float* eb2 = (const float*)d_in[4];
    const float* qw  = (const float*)d_in[5];
    const float* dw1 = (const float*)d_in[6];
    const float* db1 = (const float*)d_in[7];
    const float* dw2 = (const float*)d_in[8];
    const float* db2 = (const float*)d_in[9];
    float* out = (float*)d_out;

    int B = in_sizes[0] / 16;        // 32768
    int n_gates = in_sizes[5] / 3;   // 32
    int NL = n_gates / 8;            // 4

    // 16 samples per 256-thread block (4 waves x 4 samples/wave) -> 8192 waves
    int blocks = (B + 15) / 16;
    qdqn_kernel<<<blocks, 256, 0, stream>>>(x, ew1, eb1, ew2, eb2, qw,
                                            dw1, db1, dw2, db2, out, B, NL);
}